// Round 3
// baseline (599.458 us; speedup 1.0000x reference)
//
#include <hip/hip_runtime.h>
#include <hip/hip_bf16.h>

#define SEQ   4096
#define BATCH 32
#define HID   512
#define MTOT  (SEQ * BATCH)   // 131072

typedef float  f32x4  __attribute__((ext_vector_type(4)));
typedef __bf16 bf16x8 __attribute__((ext_vector_type(8)));

__device__ __forceinline__ unsigned short f2bf(float f) {
    unsigned int u = __builtin_bit_cast(unsigned int, f);
    u = (u + 0x7fffu + ((u >> 16) & 1u)) >> 16;   // RNE
    return (unsigned short)u;
}

// HW packed convert: dst = (bf16(hi)<<16) | bf16(lo), RNE
__device__ __forceinline__ unsigned int cvt_pk(float lo, float hi) {
    unsigned int r;
    asm("v_cvt_pk_bf16_f32 %0, %1, %2" : "=v"(r) : "v"(lo), "v"(hi));
    return r;
}

__device__ __forceinline__ float tanh_fast(float x) {
    float ax = fabsf(x);
    float e  = __expf(-2.0f * ax);           // in (0,1]
    float t  = (1.0f - e) * __builtin_amdgcn_rcpf(1.0f + e);
    return copysignf(t, x);
}

// ---- kernel 1: W fp32 -> bf16 ------------------------------------------
__global__ __launch_bounds__(256) void cvt_w_kernel(const float* __restrict__ W,
                                                    unsigned short* __restrict__ Wb) {
    int i = (blockIdx.x * 256 + threadIdx.x) * 4;
    float4 f = *(const float4*)(W + i);
    ushort4 u;
    u.x = f2bf(f.x); u.y = f2bf(f.y); u.z = f2bf(f.z); u.w = f2bf(f.w);
    *(ushort4*)(Wb + i) = u;
}

// ---- kernel 2: fused GEMM + tanh + ctx-dot -> sims ---------------------
// Structure: B-panel (64 cols x 512 K, bf16) resident in LDS, loaded ONCE.
// A fragments stream global->reg with cvt_pk at use. NO barriers in K-loop.
#define GBM 512            // rows per block  (8 waves x 64 rows)
#define GBN 64             // cols per block  (8 n-tiles)
#define NKT (HID / 32)     // 16 K-steps of 32

__global__ __launch_bounds__(512, 4) void gemm_sim_kernel(
    const float* __restrict__ x, const unsigned short* __restrict__ Wb,
    const float* __restrict__ bias, const float* __restrict__ ctx,
    float* __restrict__ sims)
{
    // 64 KB. Row o: 64 chunks of 8 bf16; LDS slot s holds global chunk s^(o&7).
    __shared__ unsigned short Bs[GBN][HID];

    // XCD-chunked: 2048 blocks, 256 wids/XCD, nt fastest -> the 8 nt-siblings
    // of one mt run in lockstep on ONE XCD (A panel L2-served after 1st fetch).
    const int bid = blockIdx.x;
    const int wid = (bid & 7) * 256 + (bid >> 3);
    const int nt  = wid & 7;          // 0..7
    const int mt  = wid >> 3;         // 0..255

    const int tid  = threadIdx.x;
    const int lane = tid & 63;
    const int w    = tid >> 6;        // wave 0..7, owns rows w*64..w*64+63
    const int l15  = lane & 15, q = lane >> 4;

    // A addressing: lane reads rows (w*64 + mi*16 + l15), k = kt*32 + q*8 .. +8
    const float* aw = x + ((size_t)mt * GBM + w * 64 + l15) * HID + q * 8;

    // ---- prefetch A for kt=0 (overlaps the B-panel DMA) ----
    float4 pa[8];
    #pragma unroll
    for (int mi = 0; mi < 4; ++mi) {
        const float4* s = (const float4*)(aw + (size_t)mi * 16 * HID);
        pa[mi * 2 + 0] = s[0];
        pa[mi * 2 + 1] = s[1];
    }

    // ---- B panel -> LDS: one wave-instr fills one 1 KB row (linear dest),
    //      global src pre-swizzled: lane l holds chunk l^(o&7) ----
    #pragma unroll
    for (int j = 0; j < 8; ++j) {
        const int o = w * 8 + j;
        const unsigned short* src =
            Wb + (size_t)(nt * GBN + o) * HID + (lane ^ (o & 7)) * 8;
        __builtin_amdgcn_global_load_lds(
            (const __attribute__((address_space(1))) void*)src,
            (__attribute__((address_space(3))) void*)(&Bs[o][0]), 16, 0, 0);
    }
    __syncthreads();   // the ONLY barrier

    f32x4 acc[4][4] = {};

    for (int kt = 0; kt < NKT; ++kt) {
        // convert prefetched A (waits the loads issued last iteration)
        bf16x8 af[4];
        #pragma unroll
        for (int mi = 0; mi < 4; ++mi) {
            uint4 u;
            u.x = cvt_pk(pa[mi*2].x,   pa[mi*2].y);
            u.y = cvt_pk(pa[mi*2].z,   pa[mi*2].w);
            u.z = cvt_pk(pa[mi*2+1].x, pa[mi*2+1].y);
            u.w = cvt_pk(pa[mi*2+1].z, pa[mi*2+1].w);
            af[mi] = __builtin_bit_cast(bf16x8, u);
        }
        // issue next-step A loads (fly across the MFMA phase below)
        if (kt < NKT - 1) {
            #pragma unroll
            for (int mi = 0; mi < 4; ++mi) {
                const float4* s =
                    (const float4*)(aw + (size_t)mi * 16 * HID + (kt + 1) * 32);
                pa[mi * 2 + 0] = s[0];
                pa[mi * 2 + 1] = s[1];
            }
        }
        // B fragments from LDS (un-swizzle; conflict-free: 8 quads x 8 lanes)
        bf16x8 bfr[4];
        #pragma unroll
        for (int ni = 0; ni < 4; ++ni) {
            const int o    = ni * 16 + l15;
            const int slot = (kt * 4 + q) ^ (o & 7);
            bfr[ni] = *(const bf16x8*)&Bs[o][slot * 8];
        }
        #pragma unroll
        for (int mi = 0; mi < 4; ++mi)
            #pragma unroll
            for (int ni = 0; ni < 4; ++ni)
                acc[mi][ni] = __builtin_amdgcn_mfma_f32_16x16x32_bf16(
                    af[mi], bfr[ni], acc[mi][ni], 0, 0, 0);
    }

    // epilogue: ctx-weighted tanh partial over this block's 64 cols
    float ps[16];
    #pragma unroll
    for (int mi = 0; mi < 4; ++mi)
        #pragma unroll
        for (int r = 0; r < 4; ++r) {
            float s = 0.f;
            #pragma unroll
            for (int ni = 0; ni < 4; ++ni) {
                const int o = nt * GBN + ni * 16 + l15;
                float y = acc[mi][ni][r] + bias[o];
                s += ctx[o] * tanh_fast(y);
            }
            ps[mi * 4 + r] = s;
        }
    #pragma unroll
    for (int off = 1; off < 16; off <<= 1)
        #pragma unroll
        for (int i = 0; i < 16; ++i)
            ps[i] += __shfl_xor(ps[i], off, 64);
    if (l15 == 0) {
        #pragma unroll
        for (int mi = 0; mi < 4; ++mi)
            #pragma unroll
            for (int r = 0; r < 4; ++r) {
                const int m = mt * GBM + w * 64 + mi * 16 + q * 4 + r;
                // sims transposed: [b][s]  (m = s*32 + b)
                atomicAdd(&sims[(size_t)(m & (BATCH - 1)) * SEQ + (m >> 5)],
                          ps[mi * 4 + r]);
            }
    }
}

// ---- kernel 3: softmax over seq, per batch (coalesced [b][s] layout) ----
__global__ __launch_bounds__(256) void softmax_kernel(const float* __restrict__ sims,
                                                      float* __restrict__ probs) {
    const int b = blockIdx.x;
    const int tid = threadIdx.x;
    const int lane = tid & 63, wave = tid >> 6;
    __shared__ float red[4];

    float v[16];
    #pragma unroll
    for (int i = 0; i < 16; ++i) v[i] = sims[(size_t)b * SEQ + i * 256 + tid];

    float mx = -INFINITY;
    #pragma unroll
    for (int i = 0; i < 16; ++i) mx = fmaxf(mx, v[i]);
    #pragma unroll
    for (int off = 32; off >= 1; off >>= 1) mx = fmaxf(mx, __shfl_xor(mx, off, 64));
    if (lane == 0) red[wave] = mx;
    __syncthreads();
    mx = fmaxf(fmaxf(red[0], red[1]), fmaxf(red[2], red[3]));
    __syncthreads();

    float sum = 0.f;
    #pragma unroll
    for (int i = 0; i < 16; ++i) { v[i] = __expf(v[i] - mx); sum += v[i]; }
    #pragma unroll
    for (int off = 32; off >= 1; off >>= 1) sum += __shfl_xor(sum, off, 64);
    if (lane == 0) red[wave] = sum;
    __syncthreads();
    const float inv = 1.0f / (red[0] + red[1] + red[2] + red[3]);

    #pragma unroll
    for (int i = 0; i < 16; ++i)
        probs[(size_t)b * SEQ + i * 256 + tid] = v[i] * inv;
}

// ---- kernel 4: weighted-sum pooling, grid-stride -----------------------
// Thread owns a fixed (b, h-quad); strides over s. Weight is wave-uniform.
// 2048 blocks x 256 thr, unroll 8 -> deep MLP; 4 atomics/thread at the end.
__global__ __launch_bounds__(256) void attend_kernel(const float* __restrict__ x,
                                                     const float* __restrict__ probs,
                                                     float* __restrict__ out) {
    const int    t  = blockIdx.x * 256 + threadIdx.x;   // 0..524287
    const size_t f0 = (size_t)t * 4;
    const int    bh = (int)(f0 & 16383);                // b*512 + h (constant)
    const int    b  = bh >> 9;

    f32x4 acc = {};
    #pragma unroll 8
    for (int i = 0; i < 32; ++i) {
        const size_t f = f0 + (size_t)i * (1u << 21);   // +128 s-rows per step
        const int    s = (int)(f >> 14);
        const float  w = probs[(size_t)b * SEQ + s];
        f32x4 v = *(const f32x4*)(x + f);
        acc += v * w;
    }
    float* o = out + bh;
    atomicAdd(o + 0, acc[0]);
    atomicAdd(o + 1, acc[1]);
    atomicAdd(o + 2, acc[2]);
    atomicAdd(o + 3, acc[3]);
}

extern "C" void kernel_launch(void* const* d_in, const int* in_sizes, int n_in,
                              void* d_out, int out_size, void* d_ws, size_t ws_size,
                              hipStream_t stream) {
    const float* x    = (const float*)d_in[0];
    const float* W    = (const float*)d_in[1];
    const float* bias = (const float*)d_in[2];
    const float* ctx  = (const float*)d_in[3];
    float* out = (float*)d_out;

    unsigned short* Wb = (unsigned short*)d_ws;                        // 512 KB
    float* sims  = (float*)((char*)d_ws + (512 << 10));                // 512 KB
    float* probs = (float*)((char*)d_ws + (1024 << 10));               // 512 KB

    hipMemsetAsync(sims, 0, MTOT * sizeof(float), stream);
    hipMemsetAsync(d_out, 0, (size_t)out_size * sizeof(float), stream);

    cvt_w_kernel<<<256, 256, 0, stream>>>(W, Wb);
    gemm_sim_kernel<<<2048, 512, 0, stream>>>(x, Wb, bias, ctx, sims);
    softmax_kernel<<<32, 256, 0, stream>>>(sims, probs);
    attend_kernel<<<2048, 256, 0, stream>>>(x, probs, out);
}

// Round 5
// 459.928 us; speedup vs baseline: 1.3034x; 1.3034x over previous
//
#include <hip/hip_runtime.h>
#include <hip/hip_bf16.h>

#define SEQ   4096
#define BATCH 32
#define HID   512
#define MTOT  (SEQ * BATCH)   // 131072

typedef float  f32x4  __attribute__((ext_vector_type(4)));
typedef __bf16 bf16x8 __attribute__((ext_vector_type(8)));

__device__ __forceinline__ unsigned short f2bf(float f) {
    unsigned int u = __builtin_bit_cast(unsigned int, f);
    u = (u + 0x7fffu + ((u >> 16) & 1u)) >> 16;   // RNE
    return (unsigned short)u;
}

// HW packed convert: dst = (bf16(hi)<<16) | bf16(lo), RNE
__device__ __forceinline__ unsigned int cvt_pk(float lo, float hi) {
    unsigned int r;
    asm("v_cvt_pk_bf16_f32 %0, %1, %2" : "=v"(r) : "v"(lo), "v"(hi));
    return r;
}

// branch-free tanh: 1 - 2/(1+e^{2x}); e^{2x}=exp2(x*2*log2e).
// x->+inf: exp2->inf, rcp->0, t->1.  x->-inf: exp2->0, t->-1.  5 VALU ops.
__device__ __forceinline__ float tanh_fast(float x) {
    float e = __builtin_amdgcn_exp2f(x * 2.885390081777927f);
    return 1.0f - 2.0f * __builtin_amdgcn_rcpf(1.0f + e);
}

// ---- kernel 1: W fp32 -> bf16 ------------------------------------------
__global__ __launch_bounds__(256) void cvt_w_kernel(const float* __restrict__ W,
                                                    unsigned short* __restrict__ Wb) {
    int i = (blockIdx.x * 256 + threadIdx.x) * 4;
    float4 f = *(const float4*)(W + i);
    ushort4 u;
    u.x = f2bf(f.x); u.y = f2bf(f.y); u.z = f2bf(f.z); u.w = f2bf(f.w);
    *(ushort4*)(Wb + i) = u;
}

// ---- kernel 2: fused GEMM + tanh + ctx-dot -> sims ---------------------
// BM=128 rows x FULL N=512 per block: x read exactly ONCE device-wide.
// W re-streamed per K-step (512 KB total, L2-resident everywhere).
// sims written complete per block -> no atomics, no memset.
#define BM 128
#define BK 32
#define NKT (HID / BK)   // 16

__global__ __launch_bounds__(512, 2) void gemm_sim_kernel(
    const float* __restrict__ x, const unsigned short* __restrict__ Wb,
    const float* __restrict__ bias, const float* __restrict__ ctx,
    float* __restrict__ sims)
{
    // rows of 32 bf16 = 64 B = 4 slots of 16 B; slot s holds chunk s^(row&3)
    __shared__ unsigned short As[2][BM][BK];    // 16 KB
    __shared__ unsigned short Bs[2][HID][BK];   // 64 KB
    __shared__ float part[8][BM];               // 4 KB

    const int mt   = blockIdx.x;      // 0..1023
    const int tid  = threadIdx.x;
    const int lane = tid & 63;
    const int w    = tid >> 6;        // wave 0..7: owns o-cols w*64..w*64+63
    const int l15  = lane & 15, q = lane >> 4;

    // A staging: thread -> (row, k-chunk)
    const int arow = tid >> 2;                 // 0..127
    const int kc   = tid & 3;                  // 8-float chunk 0..3
    const int aws  = (kc ^ (arow & 3)) * 8;    // swizzled write slot (elems)
    const float* aptr = x + (size_t)(mt * BM + arow) * HID + kc * 8;

    // B staging via global_load_lds: issue j covers rows j*128 + w*16 .. +15.
    // LDS dest linear; global src pre-swizzled.
    const int brl  = lane >> 2;                // 0..15 row within 16-row group
    const int bsl  = lane & 3;                 // slot 0..3
    // per issue j: row o = j*128 + w*16 + brl ; chunk = bsl ^ (o&3)

    f32x4 acc[8][4] = {};   // [mi][ni][r]: m = mi*16+q*4+r, o = w*64+ni*16+l15

    // ---- prologue: stage kt=0 into buf 0 ----
    {
        #pragma unroll
        for (int j = 0; j < 4; ++j) {
            const int o = j * 128 + w * 16 + brl;
            const unsigned short* src =
                Wb + (size_t)o * HID + ((bsl ^ (o & 3)) * 8);
            __builtin_amdgcn_global_load_lds(
                (const __attribute__((address_space(1))) void*)src,
                (__attribute__((address_space(3))) void*)(&Bs[0][j * 128 + w * 16][0]),
                16, 0, 0);
        }
        const float4* s4 = (const float4*)aptr;
        float4 a0 = s4[0], a1 = s4[1];
        uint4 u;
        u.x = cvt_pk(a0.x, a0.y); u.y = cvt_pk(a0.z, a0.w);
        u.z = cvt_pk(a1.x, a1.y); u.w = cvt_pk(a1.z, a1.w);
        *(uint4*)&As[0][arow][aws] = u;
    }
    __syncthreads();

    for (int kt = 0; kt < NKT; ++kt) {
        const int cur = kt & 1, nxt = cur ^ 1;

        // ---- issue next-tile loads FIRST (land under MFMAs below) ----
        float4 a0, a1;
        if (kt < NKT - 1) {
            const int k0n = (kt + 1) * BK;
            #pragma unroll
            for (int j = 0; j < 4; ++j) {
                const int o = j * 128 + w * 16 + brl;
                const unsigned short* src =
                    Wb + (size_t)o * HID + k0n + ((bsl ^ (o & 3)) * 8);
                __builtin_amdgcn_global_load_lds(
                    (const __attribute__((address_space(1))) void*)src,
                    (__attribute__((address_space(3))) void*)(&Bs[nxt][j * 128 + w * 16][0]),
                    16, 0, 0);
            }
            const float4* s4 = (const float4*)(aptr + k0n);
            a0 = s4[0];
            a1 = s4[1];
        }

        // ---- compute current tile ----
        bf16x8 af[8], bfr[4];
        #pragma unroll
        for (int mi = 0; mi < 8; ++mi) {
            const int r = mi * 16 + l15;
            af[mi] = *(const bf16x8*)&As[cur][r][((q ^ (r & 3)) * 8)];
        }
        #pragma unroll
        for (int ni = 0; ni < 4; ++ni) {
            const int o = w * 64 + ni * 16 + l15;
            bfr[ni] = *(const bf16x8*)&Bs[cur][o][((q ^ (o & 3)) * 8)];
        }
        #pragma unroll
        for (int mi = 0; mi < 8; ++mi)
            #pragma unroll
            for (int ni = 0; ni < 4; ++ni)
                acc[mi][ni] = __builtin_amdgcn_mfma_f32_16x16x32_bf16(
                    af[mi], bfr[ni], acc[mi][ni], 0, 0, 0);

        // ---- convert + LDS-write next A ----
        if (kt < NKT - 1) {
            uint4 u;
            u.x = cvt_pk(a0.x, a0.y); u.y = cvt_pk(a0.z, a0.w);
            u.z = cvt_pk(a1.x, a1.y); u.w = cvt_pk(a1.z, a1.w);
            *(uint4*)&As[nxt][arow][aws] = u;
        }
        __syncthreads();
    }

    // ---- epilogue: ctx-weighted tanh, per-wave partial over its 64 cols ----
    float ps[32];
    #pragma unroll
    for (int mi = 0; mi < 8; ++mi)
        #pragma unroll
        for (int r = 0; r < 4; ++r) {
            float s = 0.f;
            #pragma unroll
            for (int ni = 0; ni < 4; ++ni) {
                const int o = w * 64 + ni * 16 + l15;
                float y = acc[mi][ni][r] + bias[o];
                s += ctx[o] * tanh_fast(y);
            }
            ps[mi * 4 + r] = s;
        }
    #pragma unroll
    for (int off = 1; off < 16; off <<= 1)
        #pragma unroll
        for (int i = 0; i < 32; ++i)
            ps[i] += __shfl_xor(ps[i], off, 64);
    if (l15 == 0) {
        #pragma unroll
        for (int mi = 0; mi < 8; ++mi)
            #pragma unroll
            for (int r = 0; r < 4; ++r)
                part[w][mi * 16 + q * 4 + r] = ps[mi * 4 + r];
    }
    __syncthreads();
    if (tid < BM) {
        float tot = 0.f;
        #pragma unroll
        for (int ww = 0; ww < 8; ++ww) tot += part[ww][tid];
        const int mg = mt * BM + tid;      // m = s*32 + b
        sims[(size_t)(mg & (BATCH - 1)) * SEQ + (mg >> 5)] = tot;
    }
}

// ---- kernel 3: softmax over seq, per batch (coalesced [b][s] layout) ----
__global__ __launch_bounds__(256) void softmax_kernel(const float* __restrict__ sims,
                                                      float* __restrict__ probs) {
    const int b = blockIdx.x;
    const int tid = threadIdx.x;
    const int lane = tid & 63, wave = tid >> 6;
    __shared__ float red[4];

    float v[16];
    #pragma unroll
    for (int i = 0; i < 16; ++i) v[i] = sims[(size_t)b * SEQ + i * 256 + tid];

    float mx = -INFINITY;
    #pragma unroll
    for (int i = 0; i < 16; ++i) mx = fmaxf(mx, v[i]);
    #pragma unroll
    for (int off = 32; off >= 1; off >>= 1) mx = fmaxf(mx, __shfl_xor(mx, off, 64));
    if (lane == 0) red[wave] = mx;
    __syncthreads();
    mx = fmaxf(fmaxf(red[0], red[1]), fmaxf(red[2], red[3]));
    __syncthreads();

    float sum = 0.f;
    #pragma unroll
    for (int i = 0; i < 16; ++i) { v[i] = __expf(v[i] - mx); sum += v[i]; }
    #pragma unroll
    for (int off = 32; off >= 1; off >>= 1) sum += __shfl_xor(sum, off, 64);
    if (lane == 0) red[wave] = sum;
    __syncthreads();
    const float inv = 1.0f / (red[0] + red[1] + red[2] + red[3]);

    #pragma unroll
    for (int i = 0; i < 16; ++i)
        probs[(size_t)b * SEQ + i * 256 + tid] = v[i] * inv;
}

// ---- kernel 4: weighted-sum pooling, grid-stride -----------------------
// Thread owns fixed (b, h-quad); 32 threads/quad, each walks 128 s-steps
// (stride 32 rows). Fully coalesced 8 MB stripes per step across the grid.
__global__ __launch_bounds__(256) void attend_kernel(const float* __restrict__ x,
                                                     const float* __restrict__ probs,
                                                     float* __restrict__ out) {
    const int    t  = blockIdx.x * 256 + threadIdx.x;   // 0..131071
    const size_t f0 = (size_t)t * 4;
    const int    bh = (int)(f0 & 16383);                // b*512 + h (constant)
    const int    b  = bh >> 9;
    const int    s0 = (int)(f0 >> 14);                  // 0..31

    f32x4 acc = {};
    #pragma unroll 8
    for (int i = 0; i < 128; ++i) {
        const int   s = s0 + i * 32;
        const float w = probs[(size_t)b * SEQ + s];
        f32x4 v = *(const f32x4*)(x + f0 + (size_t)i * (32u * 16384u));
        acc += v * w;
    }
    float* o = out + bh;
    atomicAdd(o + 0, acc[0]);
    atomicAdd(o + 1, acc[1]);
    atomicAdd(o + 2, acc[2]);
    atomicAdd(o + 3, acc[3]);
}

extern "C" void kernel_launch(void* const* d_in, const int* in_sizes, int n_in,
                              void* d_out, int out_size, void* d_ws, size_t ws_size,
                              hipStream_t stream) {
    const float* x    = (const float*)d_in[0];
    const float* W    = (const float*)d_in[1];
    const float* bias = (const float*)d_in[2];
    const float* ctx  = (const float*)d_in[3];
    float* out = (float*)d_out;

    unsigned short* Wb = (unsigned short*)d_ws;                        // 512 KB
    float* sims  = (float*)((char*)d_ws + (512 << 10));                // 512 KB
    float* probs = (float*)((char*)d_ws + (1024 << 10));               // 512 KB

    hipMemsetAsync(d_out, 0, (size_t)out_size * sizeof(float), stream);

    cvt_w_kernel<<<256, 256, 0, stream>>>(W, Wb);
    gemm_sim_kernel<<<1024, 512, 0, stream>>>(x, Wb, bias, ctx, sims);
    softmax_kernel<<<32, 256, 0, stream>>>(sims, probs);
    attend_kernel<<<512, 256, 0, stream>>>(x, probs, out);
}

// Round 7
// 458.563 us; speedup vs baseline: 1.3073x; 1.0030x over previous
//
#include <hip/hip_runtime.h>
#include <hip/hip_bf16.h>

#define SEQ   4096
#define BATCH 32
#define HID   512
#define MTOT  (SEQ * BATCH)   // 131072

typedef float  f32x4  __attribute__((ext_vector_type(4)));
typedef __bf16 bf16x8 __attribute__((ext_vector_type(8)));

__device__ __forceinline__ unsigned short f2bf(float f) {
    unsigned int u = __builtin_bit_cast(unsigned int, f);
    u = (u + 0x7fffu + ((u >> 16) & 1u)) >> 16;   // RNE
    return (unsigned short)u;
}

// HW packed convert: dst = (bf16(hi)<<16) | bf16(lo), RNE
__device__ __forceinline__ unsigned int cvt_pk(float lo, float hi) {
    unsigned int r;
    asm("v_cvt_pk_bf16_f32 %0, %1, %2" : "=v"(r) : "v"(lo), "v"(hi));
    return r;
}

// branch-free tanh: 1 - 2/(1+e^{2x}); e^{2x}=exp2(x*2*log2e).
__device__ __forceinline__ float tanh_fast(float x) {
    float e = __builtin_amdgcn_exp2f(x * 2.885390081777927f);
    return 1.0f - 2.0f * __builtin_amdgcn_rcpf(1.0f + e);
}

// ---- kernel 1: W fp32 -> bf16 ------------------------------------------
__global__ __launch_bounds__(256) void cvt_w_kernel(const float* __restrict__ W,
                                                    unsigned short* __restrict__ Wb) {
    int i = (blockIdx.x * 256 + threadIdx.x) * 4;
    float4 f = *(const float4*)(W + i);
    ushort4 u;
    u.x = f2bf(f.x); u.y = f2bf(f.y); u.z = f2bf(f.z); u.w = f2bf(f.w);
    *(ushort4*)(Wb + i) = u;
}

// ---- kernel 2: fused GEMM + tanh + ctx-dot -> sims ---------------------
// m97-shape: 64m x 512o per block, 4 waves (wave owns 128 o-cols), BK=64,
// single-buffered LDS (73 KB) -> 2 blocks/CU co-resident: one block's
// barrier drain overlaps the other's MFMA phase.  x read ONCE device-wide.
#define BM  64
#define BK  64
#define NKT (HID / BK)   // 8

__global__ __launch_bounds__(256, 2) void gemm_sim_kernel(
    const float* __restrict__ x, const unsigned short* __restrict__ Wb,
    const float* __restrict__ bias, const float* __restrict__ ctx,
    float* __restrict__ sims)
{
    // rows = 64 bf16 = 128 B = 8 slots of 16 B; slot s holds k-chunk s^(row&7)
    __shared__ unsigned short As[BM][BK];     // 8 KB
    __shared__ unsigned short Bs[HID][BK];    // 64 KB
    __shared__ float part[4][BM];             // 1 KB

    const int mt   = blockIdx.x;      // 0..2047
    const int tid  = threadIdx.x;
    const int lane = tid & 63;
    const int w    = tid >> 6;        // wave 0..3: owns o-cols w*128..w*128+128
    const int l15  = lane & 15, q = lane >> 4;

    // A staging: thread -> (row = tid>>2, 16-float chunk kc = tid&3)
    const int arow = tid >> 2;                 // 0..63
    const int kc   = tid & 3;                  // 0..3
    const float* aptr = x + (size_t)(mt * BM + arow) * HID + kc * 16;

    // B staging via global_load_lds: issue j covers rows j*32 + (tid>>3),
    // chunk = tid&7. LDS dest LINEAR; global src pre-swizzled by ^(row&7).
    const int br  = tid >> 3;                  // 0..31 (+j*32)
    const int bch = tid & 7;                   // 16B chunk 0..7

    f32x4 acc[4][8] = {};   // [mi][ni]: m = mi*16+q*4+r, o = w*128+ni*16+l15

    // prologue: A regs for kt=0
    float4 a[4];
    #pragma unroll
    for (int j = 0; j < 4; ++j) a[j] = ((const float4*)aptr)[j];

    for (int kt = 0; kt < NKT; ++kt) {
        const int k0 = kt * BK;

        // ---- stage B (16 x 4KB wave-linear DMA) ----
        #pragma unroll
        for (int j = 0; j < 16; ++j) {
            const int r = j * 32 + br;
            const unsigned short* src =
                Wb + (size_t)r * HID + k0 + ((bch ^ (r & 7)) * 8);
            __builtin_amdgcn_global_load_lds(
                (const __attribute__((address_space(1))) void*)src,
                (__attribute__((address_space(3))) void*)(&Bs[r][bch * 8]),
                16, 0, 0);
        }
        // ---- cvt + write A (16 floats -> 2 swizzled 16B slots) ----
        {
            uint4 u0, u1;
            u0.x = cvt_pk(a[0].x, a[0].y); u0.y = cvt_pk(a[0].z, a[0].w);
            u0.z = cvt_pk(a[1].x, a[1].y); u0.w = cvt_pk(a[1].z, a[1].w);
            u1.x = cvt_pk(a[2].x, a[2].y); u1.y = cvt_pk(a[2].z, a[2].w);
            u1.z = cvt_pk(a[3].x, a[3].y); u1.w = cvt_pk(a[3].z, a[3].w);
            const int c0 = kc * 2;
            *(uint4*)&As[arow][((c0)     ^ (arow & 7)) * 8] = u0;
            *(uint4*)&As[arow][((c0 + 1) ^ (arow & 7)) * 8] = u1;
        }
        // ---- prefetch next A (completes during barrier drain) ----
        if (kt < NKT - 1) {
            const float* ap = aptr + (kt + 1) * BK;
            #pragma unroll
            for (int j = 0; j < 4; ++j) a[j] = ((const float4*)ap)[j];
        }
        __syncthreads();   // B in LDS + A written

        // ---- compute ----
        #pragma unroll
        for (int kh = 0; kh < 2; ++kh) {
            bf16x8 af[4], bfr[8];
            #pragma unroll
            for (int mi = 0; mi < 4; ++mi) {
                const int r = mi * 16 + l15;
                af[mi] = *(const bf16x8*)&As[r][(((kh * 4 + q) ^ (r & 7)) * 8)];
            }
            #pragma unroll
            for (int ni = 0; ni < 8; ++ni) {
                const int o = w * 128 + ni * 16 + l15;
                bfr[ni] = *(const bf16x8*)&Bs[o][(((kh * 4 + q) ^ (o & 7)) * 8)];
            }
            #pragma unroll
            for (int mi = 0; mi < 4; ++mi)
                #pragma unroll
                for (int ni = 0; ni < 8; ++ni)
                    acc[mi][ni] = __builtin_amdgcn_mfma_f32_16x16x32_bf16(
                        af[mi], bfr[ni], acc[mi][ni], 0, 0, 0);
        }
        __syncthreads();   // all reads done before next overwrite
    }

    // ---- epilogue: ctx-weighted tanh partial over this wave's 128 cols ----
    float ps[16];
    #pragma unroll
    for (int mi = 0; mi < 4; ++mi)
        #pragma unroll
        for (int r = 0; r < 4; ++r) {
            float s = 0.f;
            #pragma unroll
            for (int ni = 0; ni < 8; ++ni) {
                const int o = w * 128 + ni * 16 + l15;
                float y = acc[mi][ni][r] + bias[o];
                s += ctx[o] * tanh_fast(y);
            }
            ps[mi * 4 + r] = s;
        }
    #pragma unroll
    for (int off = 1; off < 16; off <<= 1)
        #pragma unroll
        for (int i = 0; i < 16; ++i)
            ps[i] += __shfl_xor(ps[i], off, 64);
    if (l15 == 0) {
        #pragma unroll
        for (int mi = 0; mi < 4; ++mi)
            #pragma unroll
            for (int r = 0; r < 4; ++r)
                part[w][mi * 16 + q * 4 + r] = ps[mi * 4 + r];
    }
    __syncthreads();
    if (tid < BM) {
        float tot = part[0][tid] + part[1][tid] + part[2][tid] + part[3][tid];
        const int m = mt * BM + tid;      // m = s*32 + b
        sims[(size_t)(m & (BATCH - 1)) * SEQ + (m >> 5)] = tot;
    }
}

// ---- kernel 3: softmax over seq, per batch (coalesced [b][s] layout) ----
__global__ __launch_bounds__(256) void softmax_kernel(const float* __restrict__ sims,
                                                      float* __restrict__ probs) {
    const int b = blockIdx.x;
    const int tid = threadIdx.x;
    const int lane = tid & 63, wave = tid >> 6;
    __shared__ float red[4];

    float v[16];
    #pragma unroll
    for (int i = 0; i < 16; ++i) v[i] = sims[(size_t)b * SEQ + i * 256 + tid];

    float mx = -INFINITY;
    #pragma unroll
    for (int i = 0; i < 16; ++i) mx = fmaxf(mx, v[i]);
    #pragma unroll
    for (int off = 32; off >= 1; off >>= 1) mx = fmaxf(mx, __shfl_xor(mx, off, 64));
    if (lane == 0) red[wave] = mx;
    __syncthreads();
    mx = fmaxf(fmaxf(red[0], red[1]), fmaxf(red[2], red[3]));
    __syncthreads();

    float sum = 0.f;
    #pragma unroll
    for (int i = 0; i < 16; ++i) { v[i] = __expf(v[i] - mx); sum += v[i]; }
    #pragma unroll
    for (int off = 32; off >= 1; off >>= 1) sum += __shfl_xor(sum, off, 64);
    if (lane == 0) red[wave] = sum;
    __syncthreads();
    const float inv = 1.0f / (red[0] + red[1] + red[2] + red[3]);

    #pragma unroll
    for (int i = 0; i < 16; ++i)
        probs[(size_t)b * SEQ + i * 256 + tid] = v[i] * inv;
}

// ---- kernel 4: weighted-sum pooling, deep-MLP --------------------------
// Thread owns (b, h-quad, 32-s chunk). Loads issued in batches of 16
// (256 B/lane in flight, no fmac between) -> ~256 KB in flight per CU.
__global__ __launch_bounds__(256, 4) void attend_kernel(const float* __restrict__ x,
                                                        const float* __restrict__ probs,
                                                        float* __restrict__ out) {
    const int bid = blockIdx.x;          // 0..2047
    const int tid = threadIdx.x;
    const int sc  = bid & 127;           // s-chunk of 32
    const int bp  = bid >> 7;            // 0..15
    const int hq  = tid & 127;           // h-quad 0..127 (lane-consecutive)
    const int b   = bp * 2 + (tid >> 7);
    const int s0  = sc * 32;

    // 32 probs for this (b, s-chunk): 128 B contiguous per lane
    const float* pp = probs + (size_t)b * SEQ + s0;
    float4 pw[8];
    #pragma unroll
    for (int i = 0; i < 8; ++i) pw[i] = ((const float4*)pp)[i];

    const float* xp = x + ((size_t)s0 * BATCH + b) * HID + hq * 4;
    f32x4 acc = {};
    #pragma unroll
    for (int g = 0; g < 2; ++g) {
        f32x4 xv[16];
        #pragma unroll
        for (int j = 0; j < 16; ++j)
            xv[j] = *(const f32x4*)(xp + (size_t)(g * 16 + j) * BATCH * HID);
        #pragma unroll
        for (int j = 0; j < 16; ++j) {
            const int i = g * 16 + j;
            const float wgt = ((const float*)&pw[i >> 2])[i & 3];
            acc += xv[j] * wgt;
        }
    }
    float* o = out + (size_t)b * HID + hq * 4;
    atomicAdd(o + 0, acc[0]);
    atomicAdd(o + 1, acc[1]);
    atomicAdd(o + 2, acc[2]);
    atomicAdd(o + 3, acc[3]);
}

extern "C" void kernel_launch(void* const* d_in, const int* in_sizes, int n_in,
                              void* d_out, int out_size, void* d_ws, size_t ws_size,
                              hipStream_t stream) {
    const float* x    = (const float*)d_in[0];
    const float* W    = (const float*)d_in[1];
    const float* bias = (const float*)d_in[2];
    const float* ctx  = (const float*)d_in[3];
    float* out = (float*)d_out;

    unsigned short* Wb = (unsigned short*)d_ws;                        // 512 KB
    float* sims  = (float*)((char*)d_ws + (512 << 10));                // 512 KB
    float* probs = (float*)((char*)d_ws + (1024 << 10));               // 512 KB

    (void)hipMemsetAsync(d_out, 0, (size_t)out_size * sizeof(float), stream);

    cvt_w_kernel<<<256, 256, 0, stream>>>(W, Wb);
    gemm_sim_kernel<<<2048, 256, 0, stream>>>(x, Wb, bias, ctx, sims);
    softmax_kernel<<<32, 256, 0, stream>>>(sims, probs);
    attend_kernel<<<2048, 256, 0, stream>>>(x, probs, out);
}